// Round 3
// baseline (44.302 us; speedup 1.0000x reference)
//
#include <hip/hip_runtime.h>
#include <hip/hip_bf16.h>
#include <hip/hip_fp16.h>

#define NN 1024   // nodes
#define FD 64     // feature dim (in == out)
#define BB 32     // batch

typedef __attribute__((ext_vector_type(4))) float    f32x4;
typedef __attribute__((ext_vector_type(8))) _Float16 f16x8;

static __device__ __forceinline__ unsigned short f2hu(float x) {
  _Float16 h = (_Float16)x;
  return __builtin_bit_cast(unsigned short, h);
}
static __device__ __forceinline__ f16x8 bch(int4 v) {
  return __builtin_bit_cast(f16x8, v);
}

// ---------------- Kernel 1: h = x@W (fp32), f = h@a1, g = h@a2,
// hF = h^T in MFMA B-fragment order: unit ((b*16+jt)*8 + frag)*64 + lane,
// frag = n*2+kh holds h[o = n*16+(lane&15)][j = jt*64 + kh*32 + (lane>>4)*8 + e]
__global__ __launch_bounds__(256) void gat_k1(
    const float* __restrict__ x, const float* __restrict__ W,
    const float* __restrict__ av, float* __restrict__ fv,
    float* __restrict__ gv, unsigned short* __restrict__ hF)
{
  __shared__ __align__(16) float Wl[FD * FD];          // 16 KB
  __shared__ __align__(16) float xl[FD * 68];          // padded rows
  __shared__ __align__(16) unsigned short tl[FD * 64]; // h^T tile fp16, chunk-swizzled
  __shared__ __align__(16) float al[2 * FD];

  const int tid = threadIdx.x;
  const int b   = blockIdx.x >> 4;
  const int n0  = (blockIdx.x & 15) << 6;

  if (tid < 32) ((f32x4*)al)[tid] = ((const f32x4*)av)[tid];
  {
    const int r  = tid >> 2;
    const int cb = (tid & 3) << 2;
    const f32x4* Wg = (const f32x4*)W;
    const f32x4* xg = (const f32x4*)(x + ((size_t)(b * NN + n0)) * FD);
#pragma unroll
    for (int k = 0; k < 4; ++k) {
      f32x4 wv = Wg[r * 16 + cb + k];
      f32x4 xv = xg[r * 16 + cb + k];
      *(f32x4*)(Wl + r * FD + ((cb + k) << 2)) = wv;
      *(f32x4*)(xl + r * 68 + ((cb + k) << 2)) = xv;
    }
  }
  __syncthreads();

  const int r  = tid >> 2;          // row (local j) in tile
  const int o0 = (tid & 3) << 4;    // 16 output features
  float acc[16];
#pragma unroll
  for (int i = 0; i < 16; ++i) acc[i] = 0.f;

#pragma unroll 8
  for (int f = 0; f < FD; ++f) {
    float xv = xl[r * 68 + f];
    const f32x4* wr = (const f32x4*)(Wl + f * FD + o0);
#pragma unroll
    for (int c = 0; c < 4; ++c) {
      f32x4 wv = wr[c];
      acc[c * 4 + 0] += xv * wv.x;
      acc[c * 4 + 1] += xv * wv.y;
      acc[c * 4 + 2] += xv * wv.z;
      acc[c * 4 + 3] += xv * wv.w;
    }
  }

  float fp = 0.f, gp = 0.f;
#pragma unroll
  for (int i = 0; i < 16; ++i) {
    fp += acc[i] * al[o0 + i];
    gp += acc[i] * al[FD + o0 + i];
  }
  fp += __shfl_xor(fp, 1); fp += __shfl_xor(fp, 2);
  gp += __shfl_xor(gp, 1); gp += __shfl_xor(gp, 2);
  if ((tid & 3) == 0) {
    fv[b * NN + n0 + r] = fp;
    gv[b * NN + n0 + r] = gp;
  }

  // h^T into LDS: element (o, r) at f16 index o*64 + (((r>>3)^(o&7))<<3) + (r&7)
#pragma unroll
  for (int i = 0; i < 16; ++i) {
    int o = o0 + i;
    tl[o * 64 + ((((r >> 3) ^ (o & 7)) << 3) | (r & 7))] = f2hu(acc[i]);
  }
  __syncthreads();

  // fragment-order output, coalesced 16B/lane
  {
    const int jt = n0 >> 6;
#pragma unroll
    for (int hh = 0; hh < 2; ++hh) {
      int u = tid + (hh << 8);
      int frag = u >> 6, l = u & 63;
      int o = ((frag >> 1) << 4) + (l & 15);
      int c = ((frag & 1) << 2) + (l >> 4);
      int4 v = *(const int4*)(tl + o * 64 + ((c ^ (o & 7)) << 3));
      *(int4*)(hF + ((((size_t)(b * 16 + jt)) * 8 + frag) * 64 + l) * 8) = v;
    }
  }
}

// ---------------- Kernel 2: fused masked-softmax attention + PV + elu
// 512 blocks, 4 fully independent waves (16 rows x 64 cols each), ZERO barriers
// in the main loop. A-fragments built in-register; B-fragments from hF.
__global__ __launch_bounds__(256) void gat_k2(
    const int* __restrict__ adj, const float* __restrict__ fv,
    const float* __restrict__ gv, const unsigned short* __restrict__ hF,
    float* __restrict__ out)
{
  __shared__ __align__(16) float gl[NN];   // g row for this batch (4 KB)
  __shared__ float red[4];

  const int tid  = threadIdx.x;
  const int b    = blockIdx.x >> 4;
  const int i0   = (blockIdx.x & 15) << 6;
  const int lane = tid & 63, w = tid >> 6;
  const int m16  = lane & 15, hi = lane >> 4;
  const int bN   = b * NN;

  // ---- prologue: stage g, per-block shift Cb = lrelu(max f_tile + max g)
  f32x4 g4 = *(const f32x4*)(gv + bN + tid * 4);
  *(f32x4*)(gl + tid * 4) = g4;
  float gm = fmaxf(fmaxf(g4.x, g4.y), fmaxf(g4.z, g4.w));
  float fm = fv[bN + i0 + lane];
#pragma unroll
  for (int m = 1; m < 64; m <<= 1) {
    gm = fmaxf(gm, __shfl_xor(gm, m));
    fm = fmaxf(fm, __shfl_xor(fm, m));
  }
  if (lane == 0) red[w] = gm;
  const float fr = fv[bN + i0 + w * 16 + m16];
  __syncthreads();
  gm = fmaxf(fmaxf(red[0], red[1]), fmaxf(red[2], red[3]));
  const float sm = fm + gm;
  const float Cb = fmaxf(sm, 0.2f * sm);  // >= max masked score; p = exp(e-Cb) <= 1

  const int*  adjP = adj + ((size_t)(bN + i0 + w * 16 + m16)) * NN + hi * 8;
  const int4* hFb  = (const int4*)hF + (size_t)b * 8192 + lane;

  float dAcc = 0.f;
  f32x4 acc[4];
#pragma unroll
  for (int n = 0; n < 4; ++n) acc[n] = (f32x4){0.f, 0.f, 0.f, 0.f};

  int4 Aa0, Aa1, Aa2, Aa3, Ba0, Ba1, Ba2, Ba3;

#define LADJ(P, t) do { const int o_ = (t) << 6;        \
    P##0 = *(const int4*)(adjP + o_);                   \
    P##1 = *(const int4*)(adjP + o_ + 4);               \
    P##2 = *(const int4*)(adjP + o_ + 32);              \
    P##3 = *(const int4*)(adjP + o_ + 36); } while (0)

#define PCOMP(dst, ia, ib, ga, gb) do {                                    \
    float e0 = fr + ga.x, e1 = fr + ga.y, e2 = fr + ga.z, e3 = fr + ga.w;  \
    float e4 = fr + gb.x, e5 = fr + gb.y, e6 = fr + gb.z, e7 = fr + gb.w;  \
    e0 = fmaxf(e0, 0.2f * e0) - Cb; e1 = fmaxf(e1, 0.2f * e1) - Cb;        \
    e2 = fmaxf(e2, 0.2f * e2) - Cb; e3 = fmaxf(e3, 0.2f * e3) - Cb;        \
    e4 = fmaxf(e4, 0.2f * e4) - Cb; e5 = fmaxf(e5, 0.2f * e5) - Cb;        \
    e6 = fmaxf(e6, 0.2f * e6) - Cb; e7 = fmaxf(e7, 0.2f * e7) - Cb;        \
    float p0 = (ia.x > 0) ? __expf(e0) : 0.f;                              \
    float p1 = (ia.y > 0) ? __expf(e1) : 0.f;                              \
    float p2 = (ia.z > 0) ? __expf(e2) : 0.f;                              \
    float p3 = (ia.w > 0) ? __expf(e3) : 0.f;                              \
    float p4 = (ib.x > 0) ? __expf(e4) : 0.f;                              \
    float p5 = (ib.y > 0) ? __expf(e5) : 0.f;                              \
    float p6 = (ib.z > 0) ? __expf(e6) : 0.f;                              \
    float p7 = (ib.w > 0) ? __expf(e7) : 0.f;                              \
    dAcc += ((p0 + p1) + (p2 + p3)) + ((p4 + p5) + (p6 + p7));             \
    dst = (f16x8){(_Float16)p0, (_Float16)p1, (_Float16)p2, (_Float16)p3,  \
                  (_Float16)p4, (_Float16)p5, (_Float16)p6, (_Float16)p7}; \
  } while (0)

#define TILE(P, t) do {                                                    \
    const int jb_ = (t) << 6;                                              \
    const int4* hp_ = hFb + (size_t)(t) * 512;                             \
    int4 h0_ = hp_[0],   h1_ = hp_[64],  h2_ = hp_[128], h3_ = hp_[192];   \
    int4 h4_ = hp_[256], h5_ = hp_[320], h6_ = hp_[384], h7_ = hp_[448];   \
    f32x4 ga0_ = *(const f32x4*)(gl + jb_ + hi * 8);                       \
    f32x4 ga1_ = *(const f32x4*)(gl + jb_ + hi * 8 + 4);                   \
    f32x4 gb0_ = *(const f32x4*)(gl + jb_ + 32 + hi * 8);                  \
    f32x4 gb1_ = *(const f32x4*)(gl + jb_ + 32 + hi * 8 + 4);              \
    f16x8 pa_, pb_;                                                        \
    PCOMP(pa_, P##0, P##1, ga0_, ga1_);                                    \
    PCOMP(pb_, P##2, P##3, gb0_, gb1_);                                    \
    acc[0] = __builtin_amdgcn_mfma_f32_16x16x32_f16(pa_, bch(h0_), acc[0], 0, 0, 0); \
    acc[0] = __builtin_amdgcn_mfma_f32_16x16x32_f16(pb_, bch(h1_), acc[0], 0, 0, 0); \
    acc[1] = __builtin_amdgcn_mfma_f32_16x16x32_f16(pa_, bch(h2_), acc[1], 0, 0, 0); \
    acc[1] = __builtin_amdgcn_mfma_f32_16x16x32_f16(pb_, bch(h3_), acc[1], 0, 0, 0); \
    acc[2] = __builtin_amdgcn_mfma_f32_16x16x32_f16(pa_, bch(h4_), acc[2], 0, 0, 0); \
    acc[2] = __builtin_amdgcn_mfma_f32_16x16x32_f16(pb_, bch(h5_), acc[2], 0, 0, 0); \
    acc[3] = __builtin_amdgcn_mfma_f32_16x16x32_f16(pa_, bch(h6_), acc[3], 0, 0, 0); \
    acc[3] = __builtin_amdgcn_mfma_f32_16x16x32_f16(pb_, bch(h7_), acc[3], 0, 0, 0); \
  } while (0)

  LADJ(Aa, 0);
  for (int tt = 0; tt < 8; ++tt) {
    LADJ(Ba, 2 * tt + 1);        // prefetch next adj tile (HBM)
    TILE(Aa, 2 * tt);
    if (tt < 7) LADJ(Aa, 2 * tt + 2);
    TILE(Ba, 2 * tt + 1);
  }

  // denominator: reduce over the 4 hi-groups sharing each row; no LDS needed
  dAcc += __shfl_xor(dAcc, 16);
  dAcc += __shfl_xor(dAcc, 32);

  float* outB = out + ((size_t)(bN + i0 + w * 16)) * FD;
#pragma unroll
  for (int rr = 0; rr < 4; ++rr) {
    const int lr = hi * 4 + rr;           // local row (C/D layout)
    float d   = __shfl(dAcc, lr);
    float inv = d > 0.f ? 1.f / d : 0.f;
#pragma unroll
    for (int n = 0; n < 4; ++n) {
      float v = acc[n][rr] * inv;
      v = v > 0.f ? v : (__expf(v) - 1.f);  // elu (alpha=1)
      outB[(size_t)lr * FD + n * 16 + m16] = v;
    }
  }
#undef LADJ
#undef PCOMP
#undef TILE
}

extern "C" void kernel_launch(void* const* d_in, const int* in_sizes, int n_in,
                              void* d_out, int out_size, void* d_ws, size_t ws_size,
                              hipStream_t stream) {
  const float* x   = (const float*)d_in[0];
  const int*   adj = (const int*)d_in[1];
  const float* W   = (const float*)d_in[2];
  const float* a   = (const float*)d_in[3];
  float* out = (float*)d_out;

  // workspace: hF fp16 fragment-ordered [B][16][8][64][8] (4 MB) | f | g
  unsigned short* hF = (unsigned short*)d_ws;
  float* fv = (float*)((char*)d_ws + (size_t)BB * FD * NN * 2);
  float* gv = fv + (size_t)BB * NN;

  gat_k1<<<dim3(BB * 16), dim3(256), 0, stream>>>(x, W, a, fv, gv, hF);
  gat_k2<<<dim3(BB * 16), dim3(256), 0, stream>>>(adj, fv, gv, hF, out);
}